// Round 4
// baseline (614.132 us; speedup 1.0000x reference)
//
#include <hip/hip_runtime.h>
#include <hip/hip_bf16.h>

#define NNODES 50000
#define NEDGES 800000
#define NDIM   128
#define EDIM   64
#define K1     192   // NDIM + EDIM
#define K2     256   // 2*NDIM
#define NB     196   // ceil(NNODES/256) scan blocks

#define KPA 136      // LDS k-stride for K=128 (node kernel)
#define KPU 264      // LDS k-stride for K=256 (node kernel)
#define MSTR 132     // LDS col-stride (floats) for 16-row scan tile

#define WAIT_LGKM 0xC07F   // s_waitcnt lgkmcnt(0), vmcnt/expcnt ignored

typedef __attribute__((ext_vector_type(8))) short bf16x8;
typedef __attribute__((ext_vector_type(4))) short bf16x4;
typedef __attribute__((ext_vector_type(4))) float f32x4;

__device__ inline short f2bf(float f) {
  union { float f; unsigned u; } v; v.f = f;
  unsigned r = v.u + 0x7FFFu + ((v.u >> 16) & 1u);   // round-to-nearest-even
  return (short)(r >> 16);
}

__device__ inline bf16x4 pack4(float4 v) {
  bf16x4 p;
  p[0] = f2bf(v.x); p[1] = f2bf(v.y); p[2] = f2bf(v.z); p[3] = f2bf(v.w);
  return p;
}

__device__ inline bf16x8 pack8(float4 a, float4 b) {
  bf16x8 p;
  p[0] = f2bf(a.x); p[1] = f2bf(a.y); p[2] = f2bf(a.z); p[3] = f2bf(a.w);
  p[4] = f2bf(b.x); p[5] = f2bf(b.y); p[6] = f2bf(b.z); p[7] = f2bf(b.w);
  return p;
}

// fp32 -> bf16 streaming convert (float4 per thread)
__global__ __launch_bounds__(256) void cvt_kernel(const float* __restrict__ src,
                                                  short* __restrict__ dst, int n) {
  int i = (blockIdx.x * 256 + threadIdx.x) * 4;
  if (i < n) {
    float4 v = *(const float4*)(src + i);
    *(bf16x4*)(dst + i) = pack4(v);
  }
}

// Transpose+convert fp32 weight [K][128] -> bf16 [n][K]
__global__ __launch_bounds__(256) void wt_kernel(const float* __restrict__ w,
                                                 short* __restrict__ wt, int K) {
  int i = blockIdx.x * 256 + threadIdx.x;
  if (i < K * NDIM) {
    int k = i >> 7;
    int n = i & 127;
    wt[n * K + k] = f2bf(w[i]);
  }
}

// ---- counting-sort pipeline: sort edges by src ----
__global__ __launch_bounds__(256) void hist_kernel(const int* __restrict__ eidx,
                                                   int* __restrict__ cnt) {
  int i = blockIdx.x * 256 + threadIdx.x;
  if (i < NEDGES) atomicAdd(&cnt[eidx[i]], 1);
}

__global__ __launch_bounds__(256) void scan_reduce_kernel(const int* __restrict__ cnt,
                                                          int* __restrict__ bsum) {
  __shared__ int sh[256];
  int tid = threadIdx.x;
  int i = blockIdx.x * 256 + tid;
  sh[tid] = (i < NNODES) ? cnt[i] : 0;
  __syncthreads();
#pragma unroll
  for (int off = 128; off > 0; off >>= 1) {
    if (tid < off) sh[tid] += sh[tid + off];
    __syncthreads();
  }
  if (tid == 0) bsum[blockIdx.x] = sh[0];
}

__global__ __launch_bounds__(256) void scan_top_kernel(const int* __restrict__ bsum,
                                                       int* __restrict__ bscan) {
  __shared__ int sh[256];
  int tid = threadIdx.x;
  int v = (tid < NB) ? bsum[tid] : 0;
  sh[tid] = v;
  __syncthreads();
#pragma unroll
  for (int off = 1; off < 256; off <<= 1) {
    int t = (tid >= off) ? sh[tid - off] : 0;
    __syncthreads();
    sh[tid] += t;
    __syncthreads();
  }
  bscan[tid] = sh[tid] - v;   // exclusive
}

__global__ __launch_bounds__(256) void scan_down_kernel(int* __restrict__ cnt,
                                                        const int* __restrict__ bscan,
                                                        int* __restrict__ row_ptr) {
  __shared__ int sh[256];
  int tid = threadIdx.x;
  int i = blockIdx.x * 256 + tid;
  int v = (i < NNODES) ? cnt[i] : 0;
  sh[tid] = v;
  __syncthreads();
#pragma unroll
  for (int off = 1; off < 256; off <<= 1) {
    int t = (tid >= off) ? sh[tid - off] : 0;
    __syncthreads();
    sh[tid] += t;
    __syncthreads();
  }
  if (i < NNODES) {
    row_ptr[i] = bscan[blockIdx.x] + (sh[tid] - v);
    cnt[i] = 0;                 // reset: becomes ticket counter, ends as degree
  }
}

__global__ __launch_bounds__(256) void permute_kernel(const int* __restrict__ eidx,
                                                      const int* __restrict__ row_ptr,
                                                      int* __restrict__ cnt,
                                                      int4* __restrict__ s_edges) {
  int e = blockIdx.x * 256 + threadIdx.x;
  if (e < NEDGES) {
    int s = eidx[e];
    int d = eidx[NEDGES + e];
    int pos = row_ptr[s] + atomicAdd(&cnt[s], 1);
    s_edges[pos] = make_int4(s, d, e, 0);
  }
}

// ---- edge kernel, barrier-free: each wave owns 32 sorted edges.
//      A-fragments loaded DIRECTLY from global (16B/lane), B from L2-hot w1t.
//      Per-wave LDS scratch only for the h-transpose before the run-scan
//      (wave-lockstep: lgkmcnt wait suffices, no __syncthreads). ----
__global__ __launch_bounds__(256, 3) void edge_kernel(const short* __restrict__ nf_bf,
                                                      const float* __restrict__ edge_feats,
                                                      const int4* __restrict__ s_edges,
                                                      const short* __restrict__ w1t,
                                                      const float* __restrict__ b1,
                                                      float* __restrict__ hagg) {
  __shared__ __align__(16) float M[4][16 * MSTR];   // per-wave 16x132 fp32 scan tile
  __shared__ int srcs[4][32];

  const int tid = threadIdx.x;
  const int wv = tid >> 6;
  const int lane = tid & 63;
  const int m16 = lane & 15;
  const int quad = lane >> 4;
  const int g0 = blockIdx.x * 128 + wv * 32;   // this wave's 32 edges

  int* srcs_w = srcs[wv];
  float* Mw = M[wv];

  if (lane < 32) srcs_w[lane] = s_edges[g0 + lane].x;
  const int4 er0 = s_edges[g0 + m16];        // A row m16      (mt=0)
  const int4 er1 = s_edges[g0 + 16 + m16];   // A row 16+m16   (mt=1)

  const short* a0n = nf_bf + (size_t)er0.y * NDIM;
  const short* a1n = nf_bf + (size_t)er1.y * NDIM;
  const float* a0e = edge_feats + (size_t)er0.z * EDIM;
  const float* a1e = edge_feats + (size_t)er1.z * EDIM;

  f32x4 acc[2][8];
#pragma unroll
  for (int mt = 0; mt < 2; ++mt)
#pragma unroll
    for (int nt = 0; nt < 8; ++nt)
      acc[mt][nt] = (f32x4){0.f, 0.f, 0.f, 0.f};

#pragma unroll
  for (int ks = 0; ks < 6; ++ks) {
    const int k0 = ks * 32 + quad * 8;
    bf16x8 a0, a1;
    if (ks < 4) {
      a0 = *(const bf16x8*)(a0n + k0);
      a1 = *(const bf16x8*)(a1n + k0);
    } else {
      const int f = k0 - NDIM;               // fp32 offset into edge row
      a0 = pack8(*(const float4*)(a0e + f), *(const float4*)(a0e + f + 4));
      a1 = pack8(*(const float4*)(a1e + f), *(const float4*)(a1e + f + 4));
    }
#pragma unroll
    for (int nt = 0; nt < 8; ++nt) {
      bf16x8 b = *(const bf16x8*)(w1t + (nt * 16 + m16) * K1 + k0);
      acc[0][nt] = __builtin_amdgcn_mfma_f32_16x16x32_bf16(a0, b, acc[0][nt], 0, 0, 0);
      acc[1][nt] = __builtin_amdgcn_mfma_f32_16x16x32_bf16(a1, b, acc[1][nt], 0, 0, 0);
    }
  }

  // Two 16-row halves: bias+lrelu -> per-wave LDS, then run-aggregated scatter
#pragma unroll
  for (int mt = 0; mt < 2; ++mt) {
#pragma unroll
    for (int nt = 0; nt < 8; ++nt) {
      const int col = nt * 16 + m16;
      const float bb = b1[col];
#pragma unroll
      for (int i = 0; i < 4; ++i) {
        float v = acc[mt][nt][i] + bb;
        v = v >= 0.f ? v : 0.2f * v;
        Mw[(quad * 4 + i) * MSTR + col] = v;
      }
    }
    __builtin_amdgcn_wave_barrier();
    __builtin_amdgcn_s_waitcnt(WAIT_LGKM);   // all lanes' ds_writes landed (wave-lockstep)
    {
      const int c0 = lane;
      const int c1 = lane + 64;
      int prev = srcs_w[mt * 16];
      float A0 = Mw[c0];
      float A1 = Mw[c1];
#pragma unroll
      for (int r = 1; r < 16; ++r) {
        int s = srcs_w[mt * 16 + r];          // wave-uniform -> no divergence
        float v0 = Mw[r * MSTR + c0];
        float v1 = Mw[r * MSTR + c1];
        if (s != prev) {
          atomicAdd(&hagg[(size_t)prev * NDIM + c0], A0);
          atomicAdd(&hagg[(size_t)prev * NDIM + c1], A1);
          A0 = v0; A1 = v1; prev = s;
        } else {
          A0 += v0; A1 += v1;
        }
      }
      atomicAdd(&hagg[(size_t)prev * NDIM + c0], A0);
      atomicAdd(&hagg[(size_t)prev * NDIM + c1], A1);
    }
    __builtin_amdgcn_wave_barrier();
    __builtin_amdgcn_s_waitcnt(WAIT_LGKM);   // scan reads done before next half's writes
  }
}

// ---- node kernel: agg = hagg@W2 + deg*b2; out = lrelu(concat(x,agg)@U1+ub1)@U2+ub2 ----
__global__ __launch_bounds__(256) void node_kernel(const short* __restrict__ nf_bf,
                                                   const float* __restrict__ hagg,
                                                   const int* __restrict__ degc,
                                                   const short* __restrict__ w2t,
                                                   const float* __restrict__ b2,
                                                   const short* __restrict__ u1t,
                                                   const float* __restrict__ ub1,
                                                   const short* __restrict__ u2t,
                                                   const float* __restrict__ ub2,
                                                   float* __restrict__ out) {
  __shared__ __align__(16) short AGH[64 * KPA];   // phase1: hagg tile; phase3: h2 tile
  __shared__ __align__(16) short XU[64 * KPU];    // concat(x, agg) tile
  __shared__ float degs[64];

  const int tid = threadIdx.x;
  const int n0 = blockIdx.x * 64;

  if (tid < 64) {
    int node = n0 + tid;
    degs[tid] = (node < NNODES) ? (float)degc[node] : 0.f;
  }
  {
    int r = tid >> 2, q = tid & 3;
    int node = n0 + r; if (node >= NNODES) node = NNODES - 1;
    const float4* hp = (const float4*)(hagg + (size_t)node * NDIM) + q * 8;
    const bf16x8* xp = (const bf16x8*)(nf_bf + (size_t)node * NDIM) + q * 4;
    short* ap = AGH + r * KPA + q * 32;
    short* xq = XU + r * KPU + q * 32;
#pragma unroll
    for (int j = 0; j < 8; ++j) *(bf16x4*)(ap + j * 4) = pack4(hp[j]);
#pragma unroll
    for (int j = 0; j < 4; ++j) *(bf16x8*)(xq + j * 8) = xp[j];
  }
  __syncthreads();

  const int lane = tid & 63;
  const int wv = tid >> 6;
  const int m16 = lane & 15;
  const int quad = lane >> 4;

  f32x4 acc[4][2];

  // ---- GEMM-a: agg = AGH @ W2 (K=128) ----
#pragma unroll
  for (int mt = 0; mt < 4; ++mt)
#pragma unroll
    for (int nt = 0; nt < 2; ++nt)
      acc[mt][nt] = (f32x4){0.f, 0.f, 0.f, 0.f};
#pragma unroll
  for (int ks = 0; ks < 4; ++ks) {
    const int k0 = ks * 32 + quad * 8;
    bf16x8 b[2];
#pragma unroll
    for (int nt = 0; nt < 2; ++nt) {
      int n = wv * 32 + nt * 16 + m16;
      b[nt] = *(const bf16x8*)(w2t + n * NDIM + k0);
    }
#pragma unroll
    for (int mt = 0; mt < 4; ++mt) {
      bf16x8 a = *(const bf16x8*)(AGH + (mt * 16 + m16) * KPA + k0);
#pragma unroll
      for (int nt = 0; nt < 2; ++nt)
        acc[mt][nt] = __builtin_amdgcn_mfma_f32_16x16x32_bf16(a, b[nt], acc[mt][nt], 0, 0, 0);
    }
  }
#pragma unroll
  for (int nt = 0; nt < 2; ++nt) {
    int col = wv * 32 + nt * 16 + m16;
    float bb = b2[col];
#pragma unroll
    for (int mt = 0; mt < 4; ++mt) {
#pragma unroll
      for (int i = 0; i < 4; ++i) {
        int row = mt * 16 + quad * 4 + i;
        float v = acc[mt][nt][i] + degs[row] * bb;
        XU[row * KPU + NDIM + col] = f2bf(v);
      }
    }
  }
  __syncthreads();

  // ---- GEMM-b: t = XU @ U1 (K=256), lrelu -> AGH ----
#pragma unroll
  for (int mt = 0; mt < 4; ++mt)
#pragma unroll
    for (int nt = 0; nt < 2; ++nt)
      acc[mt][nt] = (f32x4){0.f, 0.f, 0.f, 0.f};
#pragma unroll
  for (int ks = 0; ks < 8; ++ks) {
    const int k0 = ks * 32 + quad * 8;
    bf16x8 b[2];
#pragma unroll
    for (int nt = 0; nt < 2; ++nt) {
      int n = wv * 32 + nt * 16 + m16;
      b[nt] = *(const bf16x8*)(u1t + n * K2 + k0);
    }
#pragma unroll
    for (int mt = 0; mt < 4; ++mt) {
      bf16x8 a = *(const bf16x8*)(XU + (mt * 16 + m16) * KPU + k0);
#pragma unroll
      for (int nt = 0; nt < 2; ++nt)
        acc[mt][nt] = __builtin_amdgcn_mfma_f32_16x16x32_bf16(a, b[nt], acc[mt][nt], 0, 0, 0);
    }
  }
  __syncthreads();
#pragma unroll
  for (int nt = 0; nt < 2; ++nt) {
    int col = wv * 32 + nt * 16 + m16;
    float bb = ub1[col];
#pragma unroll
    for (int mt = 0; mt < 4; ++mt) {
#pragma unroll
      for (int i = 0; i < 4; ++i) {
        int row = mt * 16 + quad * 4 + i;
        float v = acc[mt][nt][i] + bb;
        v = v >= 0.f ? v : 0.2f * v;
        AGH[row * KPA + col] = f2bf(v);
      }
    }
  }
  __syncthreads();

  // ---- GEMM-c: out = h2 @ U2 (K=128) + ub2 ----
#pragma unroll
  for (int mt = 0; mt < 4; ++mt)
#pragma unroll
    for (int nt = 0; nt < 2; ++nt)
      acc[mt][nt] = (f32x4){0.f, 0.f, 0.f, 0.f};
#pragma unroll
  for (int ks = 0; ks < 4; ++ks) {
    const int k0 = ks * 32 + quad * 8;
    bf16x8 b[2];
#pragma unroll
    for (int nt = 0; nt < 2; ++nt) {
      int n = wv * 32 + nt * 16 + m16;
      b[nt] = *(const bf16x8*)(u2t + n * NDIM + k0);
    }
#pragma unroll
    for (int mt = 0; mt < 4; ++mt) {
      bf16x8 a = *(const bf16x8*)(AGH + (mt * 16 + m16) * KPA + k0);
#pragma unroll
      for (int nt = 0; nt < 2; ++nt)
        acc[mt][nt] = __builtin_amdgcn_mfma_f32_16x16x32_bf16(a, b[nt], acc[mt][nt], 0, 0, 0);
    }
  }
#pragma unroll
  for (int nt = 0; nt < 2; ++nt) {
    int col = wv * 32 + nt * 16 + m16;
    float bb = ub2[col];
#pragma unroll
    for (int mt = 0; mt < 4; ++mt) {
#pragma unroll
      for (int i = 0; i < 4; ++i) {
        int row = mt * 16 + quad * 4 + i;
        int node = n0 + row;
        if (node < NNODES)
          out[(size_t)node * NDIM + col] = acc[mt][nt][i] + bb;
      }
    }
  }
}

extern "C" void kernel_launch(void* const* d_in, const int* in_sizes, int n_in,
                              void* d_out, int out_size, void* d_ws, size_t ws_size,
                              hipStream_t stream) {
  const float* node_feats = (const float*)d_in[0];
  const float* edge_feats = (const float*)d_in[1];
  const float* msg_w1 = (const float*)d_in[2];
  const float* msg_b1 = (const float*)d_in[3];
  const float* msg_w2 = (const float*)d_in[4];
  const float* msg_b2 = (const float*)d_in[5];
  const float* upd_w1 = (const float*)d_in[6];
  const float* upd_b1 = (const float*)d_in[7];
  const float* upd_w2 = (const float*)d_in[8];
  const float* upd_b2 = (const float*)d_in[9];
  const int* eidx = (const int*)d_in[10];

  // ws layout (16B-aligned sections)
  float* hagg   = (float*)d_ws;                        // N*128 f32
  int* cnt      = (int*)(hagg + (size_t)NNODES * NDIM);// N (zeroed with hagg)
  int* row_ptr  = cnt + NNODES;                        // N
  int* bsum     = row_ptr + NNODES;                    // 256
  int* bscan    = bsum + 256;                          // 256
  int4* s_edges = (int4*)(bscan + 256);                // E int4
  short* w1t    = (short*)(s_edges + NEDGES);          // 128*K1 bf16
  short* w2t    = w1t + 128 * K1;
  short* u1t    = w2t + 128 * 128;
  short* u2t    = u1t + 128 * K2;
  short* nf_bf  = u2t + 128 * 128;                     // N*128 bf16

  hipMemsetAsync(d_ws, 0, (size_t)(NNODES * NDIM + NNODES) * sizeof(float), stream);

  cvt_kernel<<<(NNODES * NDIM / 4 + 255) / 256, 256, 0, stream>>>(node_feats, nf_bf,
                                                                  NNODES * NDIM);
  wt_kernel<<<(K1 * 128) / 256, 256, 0, stream>>>(msg_w1, w1t, K1);
  wt_kernel<<<(128 * 128) / 256, 256, 0, stream>>>(msg_w2, w2t, 128);
  wt_kernel<<<(K2 * 128) / 256, 256, 0, stream>>>(upd_w1, u1t, K2);
  wt_kernel<<<(128 * 128) / 256, 256, 0, stream>>>(upd_w2, u2t, 128);

  hist_kernel<<<NEDGES / 256, 256, 0, stream>>>(eidx, cnt);
  scan_reduce_kernel<<<NB, 256, 0, stream>>>(cnt, bsum);
  scan_top_kernel<<<1, 256, 0, stream>>>(bsum, bscan);
  scan_down_kernel<<<NB, 256, 0, stream>>>(cnt, bscan, row_ptr);
  permute_kernel<<<NEDGES / 256, 256, 0, stream>>>(eidx, row_ptr, cnt, s_edges);

  edge_kernel<<<NEDGES / 128, 256, 0, stream>>>(nf_bf, edge_feats, s_edges,
                                                w1t, msg_b1, hagg);
  node_kernel<<<(NNODES + 63) / 64, 256, 0, stream>>>(nf_bf, hagg, cnt,
                                                      w2t, msg_b2, u1t, upd_b1,
                                                      u2t, upd_b2, (float*)d_out);
}